// Round 11
// baseline (292.247 us; speedup 1.0000x reference)
//
#include <hip/hip_runtime.h>

#define NN 100000
#define NE 1600000
#define NBUCK 782    // ceil(NN/128), bucket = node >> 7
#define BCAP 2560    // fixed bucket capacity (mean 2046, sigma ~45 -> 11 sigma headroom)
#define PCHUNK 8192  // edges per k_pairs block -> 196 chunks, x2 sides = 392 blocks
#define NPB 196      // ceil(NE/PCHUNK)
#define STAGE_CAP 12288  // k_nodes LDS staging (48 KB; bucket count <= BCAP)

struct alignas(8) US4 { unsigned short x, y, z, w; };
typedef unsigned int u32x4 __attribute__((ext_vector_type(4)));  // NT-store-able
typedef float f32x2 __attribute__((ext_vector_type(2)));         // NT-store-able

__device__ __forceinline__ float bfu(unsigned int hw) { return __uint_as_float(hw << 16); }
__device__ __forceinline__ unsigned short f2bf(float f) {
    unsigned int u = __float_as_uint(f);
    return (unsigned short)((u + 0x7fffu + ((u >> 16) & 1u)) >> 16);
}

// ---------------- build: padded-bucket edge arrays (offset cursors, no init kernel) ----------------

// side-split LDS-binned scatter into padded bucket regions.  Cursors are 0-based
// offsets within each bucket (memset to 0 on host side).
// blocks [0,NPB): dst side -> E2d = (src<<7)|(dst&127)
// blocks [NPB,2*NPB): src side -> E2s = src&127 (byte)
__global__ __launch_bounds__(512) void k_pairs(const int* __restrict__ src,
                                               const int* __restrict__ dst,
                                               int* __restrict__ cur_d,
                                               int* __restrict__ cur_s,
                                               int* __restrict__ E2d,
                                               unsigned char* __restrict__ E2s) {
    __shared__ int hist[NBUCK], gbase[NBUCK];
    int tid = threadIdx.x;
    int bid = blockIdx.x;
    bool dside = (bid < NPB);
    int chunk = dside ? bid : bid - NPB;
    const int* key = dside ? dst : src;
    int* cur = dside ? cur_d : cur_s;
    for (int i = tid; i < NBUCK; i += 512) hist[i] = 0;
    __syncthreads();
    int base = chunk * PCHUNK;
#pragma unroll
    for (int i = 0; i < PCHUNK / 512; ++i) {
        int e = base + i * 512 + tid;
        if (e < NE) atomicAdd(&hist[key[e] >> 7], 1);
    }
    __syncthreads();
    // rotate reservation start per block to decorrelate cursor-line contention
    int rot = (int)((bid * 191u) % NBUCK);
    for (int ii = tid; ii < NBUCK; ii += 512) {
        int i = ii + rot;
        if (i >= NBUCK) i -= NBUCK;
        int h = hist[i];
        if (h) gbase[i] = atomicAdd(&cur[i], h);
        hist[i] = 0;
    }
    __syncthreads();
    if (dside) {
#pragma unroll
        for (int i = 0; i < PCHUNK / 512; ++i) {
            int e = base + i * 512 + tid;
            if (e < NE) {
                int s = src[e], d = dst[e];
                int bd = d >> 7;
                int pd = atomicAdd(&hist[bd], 1);
                E2d[(size_t)bd * BCAP + gbase[bd] + pd] = (s << 7) | (d & 127);
            }
        }
    } else {
#pragma unroll
        for (int i = 0; i < PCHUNK / 512; ++i) {
            int e = base + i * 512 + tid;
            if (e < NE) {
                int s = src[e];
                int bs = s >> 7;
                int ps = atomicAdd(&hist[bs], 1);
                E2s[(size_t)bs * BCAP + gbase[bs] + ps] = (unsigned char)(s & 127);
            }
        }
    }
}

// b < NBUCK: per-bucket CSR built IN PLACE over EB (bucket staged in LDS) +
//            rowdesc[node] = (abs_row_start << 9) | deg, r_in.
// b >= NBUCK: out-degree count from E2s -> r_out.
// Bucket counts = final cursor offsets.  Block 0 also zeroes dummy rows.
__global__ __launch_bounds__(256) void k_nodes(int* __restrict__ EB,
                                               const unsigned char* __restrict__ E2s,
                                               const int* __restrict__ cur_d,
                                               const int* __restrict__ cur_s,
                                               int* __restrict__ rowdesc,
                                               float* __restrict__ r_in,
                                               float* __restrict__ r_out,
                                               unsigned short* __restrict__ A,
                                               unsigned short* __restrict__ B,
                                               unsigned short* __restrict__ C16) {
    __shared__ int cnt[128], cur[128];
    __shared__ int stage[STAGE_CAP];  // 48 KB
    int tid = threadIdx.x;
    int b = blockIdx.x;
    if (b == 0) {  // fold dummy-row zeroing into the first block
        if (tid < 64) {
            A[(size_t)NN * 64 + tid] = 0;
            B[(size_t)NN * 64 + tid] = 0;
        }
        if (tid < 16) C16[(size_t)NN * 16 + tid] = 0;
    }
    if (b >= NBUCK) {  // ---- out-degree ----
        b -= NBUCK;
        int base = b * BCAP;
        int end = base + cur_s[b];
        if (tid < 128) cnt[tid] = 0;
        __syncthreads();
        for (int i = base + tid; i < end; i += 256) atomicAdd(&cnt[E2s[i]], 1);
        __syncthreads();
        if (tid < 128) {
            int node = b * 128 + tid;
            if (node < NN) r_out[node] = rsqrtf((float)max(cnt[tid], 1));
        }
        return;
    }
    int base = b * BCAP;
    int m = min(cur_d[b], STAGE_CAP);
    if (tid < 128) cnt[tid] = 0;
    __syncthreads();
    for (int i = tid; i < m; i += 256) {
        int e = EB[base + i];
        stage[i] = e;
        atomicAdd(&cnt[e & 127], 1);
    }
    __syncthreads();
    int v = (tid < 128) ? cnt[tid] : 0;
    for (int off = 1; off < 128; off <<= 1) {
        int u = (tid >= off && tid < 128) ? cnt[tid - off] : 0;
        __syncthreads();
        if (tid < 128) cnt[tid] += u;
        __syncthreads();
    }
    if (tid < 128) {
        int excl = cnt[tid] - v;  // exclusive scan within bucket
        cur[tid] = excl;
        int node = b * 128 + tid;
        if (node < NN) {
            rowdesc[node] = ((base + excl) << 9) | min(v, 511);
            r_in[node] = rsqrtf((float)max(v, 1));
        }
    }
    __syncthreads();
    for (int i = tid; i < m; i += 256) {
        int e = stage[i];
        int pos = atomicAdd(&cur[e & 127], 1);
        EB[base + pos] = e >> 7;
    }
}

// ---------------- dense GEMMs ----------------

// A(bf16) = (x @ W0) * r_out.  128 nodes/block, thread = 8m x 4n, K=128 in two
// halves.  8-row accumulators double the FMA:LDS-read ratio vs the 4-row tile.
__global__ __launch_bounds__(256) void k_gemm0(const float* __restrict__ x,
                                               const float* __restrict__ W0,
                                               const float* __restrict__ r_out,
                                               unsigned short* __restrict__ A) {
    __shared__ float xl[128 * 65];
    __shared__ float wl[64 * 64];
    int tid = threadIdx.x;
    int m0 = blockIdx.x * 128;
    int tn = tid & 15, tm = tid >> 4;  // tm: 8-row group [0,16)
    float acc[8][4] = {};
    const float4* W4 = (const float4*)W0;
    float4* wl4 = (float4*)wl;
    for (int h = 0; h < 2; ++h) {
        __syncthreads();
#pragma unroll
        for (int i = 0; i < 8; ++i) {  // 2048 float4 chunks of the x half-K panel
            int idx = i * 256 + tid;
            int m = idx >> 4, kc = idx & 15;
            int gm = min(m0 + m, NN - 1);
            float4 v = *(const float4*)&x[(size_t)gm * 128 + h * 64 + kc * 4];
            float* p = &xl[m * 65 + kc * 4];
            p[0] = v.x; p[1] = v.y; p[2] = v.z; p[3] = v.w;
        }
#pragma unroll
        for (int i = 0; i < 4; ++i) wl4[i * 256 + tid] = W4[h * 1024 + i * 256 + tid];
        __syncthreads();
#pragma unroll 4
        for (int k = 0; k < 64; ++k) {
            float4 wv = *(const float4*)&wl[k * 64 + tn * 4];
            float xv[8];
#pragma unroll
            for (int i = 0; i < 8; ++i) xv[i] = xl[(tm * 8 + i) * 65 + k];
#pragma unroll
            for (int i = 0; i < 8; ++i) {
                acc[i][0] = fmaf(xv[i], wv.x, acc[i][0]);
                acc[i][1] = fmaf(xv[i], wv.y, acc[i][1]);
                acc[i][2] = fmaf(xv[i], wv.z, acc[i][2]);
                acc[i][3] = fmaf(xv[i], wv.w, acc[i][3]);
            }
        }
    }
#pragma unroll
    for (int i = 0; i < 8; ++i) {
        int m = m0 + tm * 8 + i;
        if (m < NN) {
            float ro = r_out[m];
            US4 o = {f2bf(acc[i][0] * ro), f2bf(acc[i][1] * ro),
                     f2bf(acc[i][2] * ro), f2bf(acc[i][3] * ro)};
            *(US4*)&A[(size_t)m * 64 + tn * 4] = o;
        }
    }
}

// C16(bf16) = ((relu(G @ W1 + b1) @ W2) * r_out).  G is bf16.  64 nodes/block.
__global__ __launch_bounds__(256) void k_mlp(const unsigned short* __restrict__ G,
                                             const float* __restrict__ W1,
                                             const float* __restrict__ b1,
                                             const float* __restrict__ W2,
                                             const float* __restrict__ r_out,
                                             unsigned short* __restrict__ C16) {
    __shared__ float gl[64 * 65];
    __shared__ float w1l[64 * 64];
    __shared__ float w2l[64 * 16];
    int tid = threadIdx.x;
    int m0 = blockIdx.x * 64;
#pragma unroll
    for (int i = 0; i < 2; ++i) {
        int idx = i * 256 + tid;  // 512 chunks of 8 bf16
        int m = idx >> 3, c8 = idx & 7;
        int gm = min(m0 + m, NN - 1);
        uint4 u = *(const uint4*)&G[(size_t)gm * 64 + c8 * 8];
        float* p = &gl[m * 65 + c8 * 8];
        p[0] = bfu(u.x & 0xffffu); p[1] = bfu(u.x >> 16);
        p[2] = bfu(u.y & 0xffffu); p[3] = bfu(u.y >> 16);
        p[4] = bfu(u.z & 0xffffu); p[5] = bfu(u.z >> 16);
        p[6] = bfu(u.w & 0xffffu); p[7] = bfu(u.w >> 16);
    }
    float4* w1l4 = (float4*)w1l;
    const float4* W1_4 = (const float4*)W1;
#pragma unroll
    for (int i = 0; i < 4; ++i) w1l4[i * 256 + tid] = W1_4[i * 256 + tid];
    ((float4*)w2l)[tid] = ((const float4*)W2)[tid];
    __syncthreads();
    int tn = tid & 15, tm = tid >> 4;
    float acc[4][4] = {};
#pragma unroll 4
    for (int k = 0; k < 64; ++k) {
        float4 wv = *(const float4*)&w1l[k * 64 + tn * 4];
        float xv[4];
#pragma unroll
        for (int i = 0; i < 4; ++i) xv[i] = gl[(tm * 4 + i) * 65 + k];
#pragma unroll
        for (int i = 0; i < 4; ++i) {
            acc[i][0] = fmaf(xv[i], wv.x, acc[i][0]);
            acc[i][1] = fmaf(xv[i], wv.y, acc[i][1]);
            acc[i][2] = fmaf(xv[i], wv.z, acc[i][2]);
            acc[i][3] = fmaf(xv[i], wv.w, acc[i][3]);
        }
    }
    float4 bb = *(const float4*)&b1[tn * 4];
    __syncthreads();
#pragma unroll
    for (int i = 0; i < 4; ++i) {
        gl[(tm * 4 + i) * 65 + tn * 4 + 0] = fmaxf(acc[i][0] + bb.x, 0.f);
        gl[(tm * 4 + i) * 65 + tn * 4 + 1] = fmaxf(acc[i][1] + bb.y, 0.f);
        gl[(tm * 4 + i) * 65 + tn * 4 + 2] = fmaxf(acc[i][2] + bb.z, 0.f);
        gl[(tm * 4 + i) * 65 + tn * 4 + 3] = fmaxf(acc[i][3] + bb.w, 0.f);
    }
    __syncthreads();
    int m = tid >> 2, n0 = (tid & 3) * 4;
    float a2[4] = {};
#pragma unroll 8
    for (int k = 0; k < 64; ++k) {
        float zv = gl[m * 65 + k];
        float4 wv = *(const float4*)&w2l[k * 16 + n0];
        a2[0] = fmaf(zv, wv.x, a2[0]);
        a2[1] = fmaf(zv, wv.y, a2[1]);
        a2[2] = fmaf(zv, wv.z, a2[2]);
        a2[3] = fmaf(zv, wv.w, a2[3]);
    }
    int node = m0 + m;
    if (node < NN) {
        float ro = r_out[node];
        US4 o = {f2bf(a2[0] * ro), f2bf(a2[1] * ro), f2bf(a2[2] * ro), f2bf(a2[3] * ro)};
        *(US4*)&C16[(size_t)node * 16 + n0] = o;
    }
}

// ---------------- gathers (register-accumulate, 2 nodes per wave) ----------------

// d=64 bf16 gather, 2 consecutive nodes/wave in lockstep.  8 lanes/edge x uint4;
// per loop body: 2 steps x 2 nodes = 4 independent h-loads + 4 csr loads in
// flight.  ALL slots >= deg clamp to zero dummy row NN (padding garbage safe).
// csr loads and o16 stores are NON-TEMPORAL: they stream once, and marking them
// nt keeps the hot h-table lines resident in L2 (the gather's binding resource).
// MODE 0: o16 = bf16(relu(agg*r_in + bias)*r_out)   (layer0 -> B)
// MODE 1: o16 = bf16(agg*r_in)                      (layer1 -> G, feeds k_mlp)
template <int MODE>
__global__ __launch_bounds__(256) void k_gb64(const int* __restrict__ rowdesc,
                                              const int* __restrict__ csr,
                                              const unsigned short* __restrict__ h,
                                              const float* __restrict__ r_in,
                                              const float* __restrict__ r_out,
                                              const float* __restrict__ bias,
                                              unsigned short* __restrict__ o16) {
    int tid = threadIdx.x;
    int wave = tid >> 6, lane = tid & 63;
    int n0 = (blockIdx.x * 4 + wave) * 2, n1 = n0 + 1;
    int rdA = rowdesc[n0], rdB = rowdesc[n1];
    int jbA = rdA >> 9, degA = rdA & 511;
    int jbB = rdB >> 9, degB = rdB & 511;
    int itn = max((degA + 7) >> 3, (degB + 7) >> 3);
    int g = lane >> 3, f8 = lane & 7;  // g: edge slot in step [0,8), f8: feature octet
    const int* cA = csr + jbA + g;
    const int* cB = csr + jbB + g;
    const unsigned short* hp = h + f8 * 8;
    float aA[8] = {}, aB[8] = {};
    for (int it = 0; it < itn; it += 2) {
        int s0 = it * 8 + g, s1 = s0 + 8;
        int eA0 = __builtin_nontemporal_load(cA + it * 8);
        int eA1 = __builtin_nontemporal_load(cA + it * 8 + 8);
        int eB0 = __builtin_nontemporal_load(cB + it * 8);
        int eB1 = __builtin_nontemporal_load(cB + it * 8 + 8);
        eA0 = (s0 < degA) ? eA0 : NN;
        eA1 = (s1 < degA) ? eA1 : NN;
        eB0 = (s0 < degB) ? eB0 : NN;
        eB1 = (s1 < degB) ? eB1 : NN;
        uint4 u0 = *(const uint4*)(hp + (size_t)eA0 * 64);
        uint4 u1 = *(const uint4*)(hp + (size_t)eA1 * 64);
        uint4 u2 = *(const uint4*)(hp + (size_t)eB0 * 64);
        uint4 u3 = *(const uint4*)(hp + (size_t)eB1 * 64);
        aA[0] += bfu(u0.x & 0xffffu); aA[1] += bfu(u0.x >> 16);
        aA[2] += bfu(u0.y & 0xffffu); aA[3] += bfu(u0.y >> 16);
        aA[4] += bfu(u0.z & 0xffffu); aA[5] += bfu(u0.z >> 16);
        aA[6] += bfu(u0.w & 0xffffu); aA[7] += bfu(u0.w >> 16);
        aA[0] += bfu(u1.x & 0xffffu); aA[1] += bfu(u1.x >> 16);
        aA[2] += bfu(u1.y & 0xffffu); aA[3] += bfu(u1.y >> 16);
        aA[4] += bfu(u1.z & 0xffffu); aA[5] += bfu(u1.z >> 16);
        aA[6] += bfu(u1.w & 0xffffu); aA[7] += bfu(u1.w >> 16);
        aB[0] += bfu(u2.x & 0xffffu); aB[1] += bfu(u2.x >> 16);
        aB[2] += bfu(u2.y & 0xffffu); aB[3] += bfu(u2.y >> 16);
        aB[4] += bfu(u2.z & 0xffffu); aB[5] += bfu(u2.z >> 16);
        aB[6] += bfu(u2.w & 0xffffu); aB[7] += bfu(u2.w >> 16);
        aB[0] += bfu(u3.x & 0xffffu); aB[1] += bfu(u3.x >> 16);
        aB[2] += bfu(u3.y & 0xffffu); aB[3] += bfu(u3.y >> 16);
        aB[4] += bfu(u3.z & 0xffffu); aB[5] += bfu(u3.z >> 16);
        aB[6] += bfu(u3.w & 0xffffu); aB[7] += bfu(u3.w >> 16);
    }
#pragma unroll
    for (int m = 8; m <= 32; m <<= 1) {
#pragma unroll
        for (int k = 0; k < 8; ++k) {
            aA[k] += __shfl_xor(aA[k], m);
            aB[k] += __shfl_xor(aB[k], m);
        }
    }
    if (g < 2) {
        int nw = g ? n1 : n0;
        float o[8];
#pragma unroll
        for (int k = 0; k < 8; ++k) o[k] = g ? aB[k] : aA[k];
        float ri = r_in[nw];
        unsigned short ov[8];
        if (MODE == 0) {
            float ro = r_out[nw];
            float4 bA = *(const float4*)&bias[f8 * 8];
            float4 bB = *(const float4*)&bias[f8 * 8 + 4];
            float bb[8] = {bA.x, bA.y, bA.z, bA.w, bB.x, bB.y, bB.z, bB.w};
#pragma unroll
            for (int k = 0; k < 8; ++k)
                ov[k] = f2bf(fmaxf(fmaf(o[k], ri, bb[k]), 0.f) * ro);
        } else {
#pragma unroll
            for (int k = 0; k < 8; ++k) ov[k] = f2bf(o[k] * ri);
        }
        u32x4 ow;
        ow.x = (unsigned)ov[0] | ((unsigned)ov[1] << 16);
        ow.y = (unsigned)ov[2] | ((unsigned)ov[3] << 16);
        ow.z = (unsigned)ov[4] | ((unsigned)ov[5] << 16);
        ow.w = (unsigned)ov[6] | ((unsigned)ov[7] << 16);
        __builtin_nontemporal_store(ow, (u32x4*)&o16[(size_t)nw * 64 + f8 * 8]);
    }
}

// d=16 bf16 gather: 2 nodes/wave, 8 lanes/edge x uint (2 feats), same structure.
// out = agg*r_in + b2 (fp32 output)
__global__ __launch_bounds__(256) void k_gb16(const int* __restrict__ rowdesc,
                                              const int* __restrict__ csr,
                                              const unsigned short* __restrict__ C16,
                                              const float* __restrict__ r_in,
                                              const float* __restrict__ b2,
                                              float* __restrict__ out) {
    int tid = threadIdx.x;
    int wave = tid >> 6, lane = tid & 63;
    int n0 = (blockIdx.x * 4 + wave) * 2, n1 = n0 + 1;
    int rdA = rowdesc[n0], rdB = rowdesc[n1];
    int jbA = rdA >> 9, degA = rdA & 511;
    int jbB = rdB >> 9, degB = rdB & 511;
    int itn = max((degA + 7) >> 3, (degB + 7) >> 3);
    int g = lane >> 3, p = lane & 7;  // p: feature pair [0,8)
    const int* cA = csr + jbA + g;
    const int* cB = csr + jbB + g;
    const unsigned short* cp = C16 + p * 2;
    float a0A = 0.f, a1A = 0.f, a0B = 0.f, a1B = 0.f;
    for (int it = 0; it < itn; it += 2) {
        int s0 = it * 8 + g, s1 = s0 + 8;
        int eA0 = __builtin_nontemporal_load(cA + it * 8);
        int eA1 = __builtin_nontemporal_load(cA + it * 8 + 8);
        int eB0 = __builtin_nontemporal_load(cB + it * 8);
        int eB1 = __builtin_nontemporal_load(cB + it * 8 + 8);
        eA0 = (s0 < degA) ? eA0 : NN;
        eA1 = (s1 < degA) ? eA1 : NN;
        eB0 = (s0 < degB) ? eB0 : NN;
        eB1 = (s1 < degB) ? eB1 : NN;
        unsigned u0 = *(const unsigned*)(cp + (size_t)eA0 * 16);
        unsigned u1 = *(const unsigned*)(cp + (size_t)eA1 * 16);
        unsigned u2 = *(const unsigned*)(cp + (size_t)eB0 * 16);
        unsigned u3 = *(const unsigned*)(cp + (size_t)eB1 * 16);
        a0A += bfu(u0 & 0xffffu); a1A += bfu(u0 >> 16);
        a0A += bfu(u1 & 0xffffu); a1A += bfu(u1 >> 16);
        a0B += bfu(u2 & 0xffffu); a1B += bfu(u2 >> 16);
        a0B += bfu(u3 & 0xffffu); a1B += bfu(u3 >> 16);
    }
#pragma unroll
    for (int m = 8; m <= 32; m <<= 1) {
        a0A += __shfl_xor(a0A, m);
        a1A += __shfl_xor(a1A, m);
        a0B += __shfl_xor(a0B, m);
        a1B += __shfl_xor(a1B, m);
    }
    if (g < 2) {
        int nw = g ? n1 : n0;
        float x0 = g ? a0B : a0A;
        float x1 = g ? a1B : a1A;
        float ri = r_in[nw];
        float2 bb = *(const float2*)&b2[p * 2];
        f32x2 o;
        o.x = fmaf(x0, ri, bb.x);
        o.y = fmaf(x1, ri, bb.y);
        __builtin_nontemporal_store(o, (f32x2*)&out[(size_t)nw * 16 + p * 2]);
    }
}

extern "C" void kernel_launch(void* const* d_in, const int* in_sizes, int n_in,
                              void* d_out, int out_size, void* d_ws, size_t ws_size,
                              hipStream_t stream) {
    const float* feats = (const float*)d_in[0];
    const int* src = (const int*)d_in[1];
    const int* dst = (const int*)d_in[2];
    const float* W0 = (const float*)d_in[3];
    const float* b0 = (const float*)d_in[4];
    const float* W1 = (const float*)d_in[5];
    const float* b1 = (const float*)d_in[6];
    const float* W2 = (const float*)d_in[7];
    const float* b2 = (const float*)d_in[8];
    float* out = (float*)d_out;

    // ws (4B units):
    //   r_out[NN] | r_in[NN] | rowdesc[NN] | EB[NBUCK*BCAP + 64] (padded buckets;
    //   E2d then csr in-place) | E2s[NBUCK*BCAP bytes] | R1[32(NN+1)] (A then G) |
    //   R2[32(NN+1)] (B) | C16[8(NN+1)] | cur_d[NBUCK] cur_s[NBUCK] (contiguous)
    float* ws = (float*)d_ws;
    float* r_out = ws;
    float* r_in = ws + NN;
    int* rowdesc = (int*)(ws + 2 * NN);
    int* EB = (int*)(ws + 3 * NN);                       // NBUCK*BCAP + 64
    size_t ebw = (size_t)NBUCK * BCAP + 64;              // words
    unsigned char* E2s = (unsigned char*)(ws + 3 * NN + ebw);
    size_t e2sw = ((size_t)NBUCK * BCAP + 3) / 4;        // words
    float* R1 = ws + 3 * NN + ebw + e2sw;
    float* R2 = R1 + (size_t)32 * (NN + 1);
    float* Creg = R2 + (size_t)32 * (NN + 1);
    int* cur_d = (int*)(Creg + (size_t)8 * (NN + 1));
    int* cur_s = cur_d + NBUCK;

    unsigned short* A = (unsigned short*)R1;
    unsigned short* G = A;  // after k_gb64<0> consumes A, region reused for G
    unsigned short* B = (unsigned short*)R2;
    unsigned short* C16 = (unsigned short*)Creg;

    // build: padded buckets, 0-based offset cursors (memset), counts = cursors
    hipMemsetAsync(cur_d, 0, 2 * NBUCK * sizeof(int), stream);
    k_pairs<<<2 * NPB, 512, 0, stream>>>(src, dst, cur_d, cur_s, EB, E2s);
    k_nodes<<<2 * NBUCK, 256, 0, stream>>>(EB, E2s, cur_d, cur_s, rowdesc, r_in, r_out,
                                           A, B, C16);

    // layer 0
    k_gemm0<<<(NN + 127) / 128, 256, 0, stream>>>(feats, W0, r_out, A);
    k_gb64<0><<<NN / 8, 256, 0, stream>>>(rowdesc, EB, A, r_in, r_out, b0, B);

    // layer 1 (+ layer2 pre-GEMM)
    k_gb64<1><<<NN / 8, 256, 0, stream>>>(rowdesc, EB, B, r_in, r_out, b0, G);
    k_mlp<<<(NN + 63) / 64, 256, 0, stream>>>(G, W1, b1, W2, r_out, C16);

    // layer 2
    k_gb16<<<NN / 8, 256, 0, stream>>>(rowdesc, EB, C16, r_in, b2, out);
}

// Round 12
// 277.888 us; speedup vs baseline: 1.0517x; 1.0517x over previous
//
#include <hip/hip_runtime.h>

#define NN 100000
#define NE 1600000
#define NBUCK 782    // ceil(NN/128), bucket = node >> 7
#define BCAP 2560    // fixed bucket capacity (mean 2046, sigma ~45 -> 11 sigma headroom)
#define PCHUNK 8192  // edges per k_pairs block -> 196 chunks, x2 sides = 392 blocks
#define NPB 196      // ceil(NE/PCHUNK)
#define STAGE_CAP 12288  // k_nodes LDS staging (48 KB; bucket count <= BCAP)

struct alignas(8) US4 { unsigned short x, y, z, w; };

__device__ __forceinline__ float bfu(unsigned int hw) { return __uint_as_float(hw << 16); }
__device__ __forceinline__ unsigned short f2bf(float f) {
    unsigned int u = __float_as_uint(f);
    return (unsigned short)((u + 0x7fffu + ((u >> 16) & 1u)) >> 16);
}

// ---------------- build: padded-bucket edge arrays (no histogram, no scan) ----------------

// 1 block: init per-side cursors to bucket bases + zero dummy rows.
__global__ __launch_bounds__(1024) void k_init(int* __restrict__ cur_d,
                                               int* __restrict__ cur_s,
                                               unsigned short* __restrict__ A,
                                               unsigned short* __restrict__ B,
                                               unsigned short* __restrict__ C16) {
    int t = threadIdx.x;
    for (int b = t; b < NBUCK; b += 1024) {
        cur_d[b] = b * BCAP;
        cur_s[b] = b * BCAP;
    }
    if (t < 64) {
        A[(size_t)NN * 64 + t] = 0;
        B[(size_t)NN * 64 + t] = 0;
    }
    if (t < 16) C16[(size_t)NN * 16 + t] = 0;
}

// side-split LDS-binned scatter into padded bucket regions.
// blocks [0,NPB): dst side -> E2d = (src<<7)|(dst&127)
// blocks [NPB,2*NPB): src side -> E2s = src&127 (byte)
__global__ __launch_bounds__(512) void k_pairs(const int* __restrict__ src,
                                               const int* __restrict__ dst,
                                               int* __restrict__ cur_d,
                                               int* __restrict__ cur_s,
                                               int* __restrict__ E2d,
                                               unsigned char* __restrict__ E2s) {
    __shared__ int hist[NBUCK], gbase[NBUCK];
    int tid = threadIdx.x;
    int bid = blockIdx.x;
    bool dside = (bid < NPB);
    int chunk = dside ? bid : bid - NPB;
    const int* key = dside ? dst : src;
    int* cur = dside ? cur_d : cur_s;
    for (int i = tid; i < NBUCK; i += 512) hist[i] = 0;
    __syncthreads();
    int base = chunk * PCHUNK;
#pragma unroll
    for (int i = 0; i < PCHUNK / 512; ++i) {
        int e = base + i * 512 + tid;
        if (e < NE) atomicAdd(&hist[key[e] >> 7], 1);
    }
    __syncthreads();
    // rotate reservation start per block to decorrelate cursor-line contention
    int rot = (int)((bid * 191u) % NBUCK);
    for (int ii = tid; ii < NBUCK; ii += 512) {
        int i = ii + rot;
        if (i >= NBUCK) i -= NBUCK;
        int h = hist[i];
        if (h) gbase[i] = atomicAdd(&cur[i], h);
        hist[i] = 0;
    }
    __syncthreads();
    if (dside) {
#pragma unroll
        for (int i = 0; i < PCHUNK / 512; ++i) {
            int e = base + i * 512 + tid;
            if (e < NE) {
                int s = src[e], d = dst[e];
                int bd = d >> 7;
                int pd = atomicAdd(&hist[bd], 1);
                E2d[gbase[bd] + pd] = (s << 7) | (d & 127);
            }
        }
    } else {
#pragma unroll
        for (int i = 0; i < PCHUNK / 512; ++i) {
            int e = base + i * 512 + tid;
            if (e < NE) {
                int s = src[e];
                int bs = s >> 7;
                int ps = atomicAdd(&hist[bs], 1);
                E2s[gbase[bs] + ps] = (unsigned char)(s & 127);
            }
        }
    }
}

// b < NBUCK: per-bucket CSR built IN PLACE over EB (bucket staged in LDS) +
//            rowdesc[node] = (abs_row_start << 9) | deg, r_in.
// b >= NBUCK: out-degree count from E2s -> r_out.
// Bucket counts recovered from final cursor values (padded layout).
__global__ __launch_bounds__(256) void k_nodes(int* __restrict__ EB,
                                               const unsigned char* __restrict__ E2s,
                                               const int* __restrict__ cur_d,
                                               const int* __restrict__ cur_s,
                                               int* __restrict__ rowdesc,
                                               float* __restrict__ r_in,
                                               float* __restrict__ r_out) {
    __shared__ int cnt[128], cur[128];
    __shared__ int stage[STAGE_CAP];  // 48 KB
    int tid = threadIdx.x;
    int b = blockIdx.x;
    if (b >= NBUCK) {  // ---- out-degree ----
        b -= NBUCK;
        int base = b * BCAP;
        int end = cur_s[b];
        if (tid < 128) cnt[tid] = 0;
        __syncthreads();
        for (int i = base + tid; i < end; i += 256) atomicAdd(&cnt[E2s[i]], 1);
        __syncthreads();
        if (tid < 128) {
            int node = b * 128 + tid;
            if (node < NN) r_out[node] = rsqrtf((float)max(cnt[tid], 1));
        }
        return;
    }
    int base = b * BCAP;
    int end = cur_d[b];
    int m = min(end - base, STAGE_CAP);
    if (tid < 128) cnt[tid] = 0;
    __syncthreads();
    for (int i = tid; i < m; i += 256) {
        int e = EB[base + i];
        stage[i] = e;
        atomicAdd(&cnt[e & 127], 1);
    }
    __syncthreads();
    int v = (tid < 128) ? cnt[tid] : 0;
    for (int off = 1; off < 128; off <<= 1) {
        int u = (tid >= off && tid < 128) ? cnt[tid - off] : 0;
        __syncthreads();
        if (tid < 128) cnt[tid] += u;
        __syncthreads();
    }
    if (tid < 128) {
        int excl = cnt[tid] - v;  // exclusive scan within bucket
        cur[tid] = excl;
        int node = b * 128 + tid;
        if (node < NN) {
            rowdesc[node] = ((base + excl) << 9) | min(v, 511);
            r_in[node] = rsqrtf((float)max(v, 1));
        }
    }
    __syncthreads();
    for (int i = tid; i < m; i += 256) {
        int e = stage[i];
        int pos = atomicAdd(&cur[e & 127], 1);
        EB[base + pos] = e >> 7;
    }
}

// ---------------- dense GEMMs ----------------

// A(bf16) = (x @ W0) * r_out.  64 nodes/block, thread = 4m x 4n, K=128 in two halves.
__global__ __launch_bounds__(256) void k_gemm0(const float* __restrict__ x,
                                               const float* __restrict__ W0,
                                               const float* __restrict__ r_out,
                                               unsigned short* __restrict__ A) {
    __shared__ float xl[64 * 129];
    __shared__ float wl[64 * 64];
    int tid = threadIdx.x;
    int m0 = blockIdx.x * 64;
#pragma unroll
    for (int i = 0; i < 8; ++i) {
        int idx = i * 256 + tid;
        int m = idx >> 5, kc = idx & 31;
        int gm = min(m0 + m, NN - 1);
        float4 v = *(const float4*)&x[(size_t)gm * 128 + kc * 4];
        float* p = &xl[m * 129 + kc * 4];
        p[0] = v.x; p[1] = v.y; p[2] = v.z; p[3] = v.w;
    }
    int tn = tid & 15, tm = tid >> 4;
    float acc[4][4] = {};
    const float4* W4 = (const float4*)W0;
    float4* wl4 = (float4*)wl;
    for (int h = 0; h < 2; ++h) {
        __syncthreads();
#pragma unroll
        for (int i = 0; i < 4; ++i) wl4[i * 256 + tid] = W4[h * 1024 + i * 256 + tid];
        __syncthreads();
#pragma unroll 4
        for (int k = 0; k < 64; ++k) {
            int kk = h * 64 + k;
            float4 wv = *(const float4*)&wl[k * 64 + tn * 4];
            float xv[4];
#pragma unroll
            for (int i = 0; i < 4; ++i) xv[i] = xl[(tm * 4 + i) * 129 + kk];
#pragma unroll
            for (int i = 0; i < 4; ++i) {
                acc[i][0] = fmaf(xv[i], wv.x, acc[i][0]);
                acc[i][1] = fmaf(xv[i], wv.y, acc[i][1]);
                acc[i][2] = fmaf(xv[i], wv.z, acc[i][2]);
                acc[i][3] = fmaf(xv[i], wv.w, acc[i][3]);
            }
        }
    }
#pragma unroll
    for (int i = 0; i < 4; ++i) {
        int m = m0 + tm * 4 + i;
        if (m < NN) {
            float ro = r_out[m];
            US4 o = {f2bf(acc[i][0] * ro), f2bf(acc[i][1] * ro),
                     f2bf(acc[i][2] * ro), f2bf(acc[i][3] * ro)};
            *(US4*)&A[(size_t)m * 64 + tn * 4] = o;
        }
    }
}

// C16(bf16) = ((relu(G @ W1 + b1) @ W2) * r_out).  G is bf16.  64 nodes/block.
__global__ __launch_bounds__(256) void k_mlp(const unsigned short* __restrict__ G,
                                             const float* __restrict__ W1,
                                             const float* __restrict__ b1,
                                             const float* __restrict__ W2,
                                             const float* __restrict__ r_out,
                                             unsigned short* __restrict__ C16) {
    __shared__ float gl[64 * 65];
    __shared__ float w1l[64 * 64];
    __shared__ float w2l[64 * 16];
    int tid = threadIdx.x;
    int m0 = blockIdx.x * 64;
#pragma unroll
    for (int i = 0; i < 2; ++i) {
        int idx = i * 256 + tid;  // 512 chunks of 8 bf16
        int m = idx >> 3, c8 = idx & 7;
        int gm = min(m0 + m, NN - 1);
        uint4 u = *(const uint4*)&G[(size_t)gm * 64 + c8 * 8];
        float* p = &gl[m * 65 + c8 * 8];
        p[0] = bfu(u.x & 0xffffu); p[1] = bfu(u.x >> 16);
        p[2] = bfu(u.y & 0xffffu); p[3] = bfu(u.y >> 16);
        p[4] = bfu(u.z & 0xffffu); p[5] = bfu(u.z >> 16);
        p[6] = bfu(u.w & 0xffffu); p[7] = bfu(u.w >> 16);
    }
    float4* w1l4 = (float4*)w1l;
    const float4* W1_4 = (const float4*)W1;
#pragma unroll
    for (int i = 0; i < 4; ++i) w1l4[i * 256 + tid] = W1_4[i * 256 + tid];
    ((float4*)w2l)[tid] = ((const float4*)W2)[tid];
    __syncthreads();
    int tn = tid & 15, tm = tid >> 4;
    float acc[4][4] = {};
#pragma unroll 4
    for (int k = 0; k < 64; ++k) {
        float4 wv = *(const float4*)&w1l[k * 64 + tn * 4];
        float xv[4];
#pragma unroll
        for (int i = 0; i < 4; ++i) xv[i] = gl[(tm * 4 + i) * 65 + k];
#pragma unroll
        for (int i = 0; i < 4; ++i) {
            acc[i][0] = fmaf(xv[i], wv.x, acc[i][0]);
            acc[i][1] = fmaf(xv[i], wv.y, acc[i][1]);
            acc[i][2] = fmaf(xv[i], wv.z, acc[i][2]);
            acc[i][3] = fmaf(xv[i], wv.w, acc[i][3]);
        }
    }
    float4 bb = *(const float4*)&b1[tn * 4];
    __syncthreads();
#pragma unroll
    for (int i = 0; i < 4; ++i) {
        gl[(tm * 4 + i) * 65 + tn * 4 + 0] = fmaxf(acc[i][0] + bb.x, 0.f);
        gl[(tm * 4 + i) * 65 + tn * 4 + 1] = fmaxf(acc[i][1] + bb.y, 0.f);
        gl[(tm * 4 + i) * 65 + tn * 4 + 2] = fmaxf(acc[i][2] + bb.z, 0.f);
        gl[(tm * 4 + i) * 65 + tn * 4 + 3] = fmaxf(acc[i][3] + bb.w, 0.f);
    }
    __syncthreads();
    int m = tid >> 2, n0 = (tid & 3) * 4;
    float a2[4] = {};
#pragma unroll 8
    for (int k = 0; k < 64; ++k) {
        float zv = gl[m * 65 + k];
        float4 wv = *(const float4*)&w2l[k * 16 + n0];
        a2[0] = fmaf(zv, wv.x, a2[0]);
        a2[1] = fmaf(zv, wv.y, a2[1]);
        a2[2] = fmaf(zv, wv.z, a2[2]);
        a2[3] = fmaf(zv, wv.w, a2[3]);
    }
    int node = m0 + m;
    if (node < NN) {
        float ro = r_out[node];
        US4 o = {f2bf(a2[0] * ro), f2bf(a2[1] * ro), f2bf(a2[2] * ro), f2bf(a2[3] * ro)};
        *(US4*)&C16[(size_t)node * 16 + n0] = o;
    }
}

// ---------------- gathers (register-accumulate, 2 nodes per wave) ----------------

// d=64 bf16 gather, 2 consecutive nodes/wave in lockstep.  8 lanes/edge x uint4;
// per loop body: 2 steps x 2 nodes = 4 independent h-loads + 4 csr loads in
// flight.  ALL slots >= deg clamp to zero dummy row NN (padding garbage safe).
// MODE 0: o16 = bf16(relu(agg*r_in + bias)*r_out)   (layer0 -> B)
// MODE 1: o16 = bf16(agg*r_in)                      (layer1 -> G, feeds k_mlp)
template <int MODE>
__global__ __launch_bounds__(256) void k_gb64(const int* __restrict__ rowdesc,
                                              const int* __restrict__ csr,
                                              const unsigned short* __restrict__ h,
                                              const float* __restrict__ r_in,
                                              const float* __restrict__ r_out,
                                              const float* __restrict__ bias,
                                              unsigned short* __restrict__ o16) {
    int tid = threadIdx.x;
    int wave = tid >> 6, lane = tid & 63;
    int n0 = (blockIdx.x * 4 + wave) * 2, n1 = n0 + 1;
    int rdA = rowdesc[n0], rdB = rowdesc[n1];
    int jbA = rdA >> 9, degA = rdA & 511;
    int jbB = rdB >> 9, degB = rdB & 511;
    int itn = max((degA + 7) >> 3, (degB + 7) >> 3);
    int g = lane >> 3, f8 = lane & 7;  // g: edge slot in step [0,8), f8: feature octet
    const int* cA = csr + jbA + g;
    const int* cB = csr + jbB + g;
    const unsigned short* hp = h + f8 * 8;
    float aA[8] = {}, aB[8] = {};
    for (int it = 0; it < itn; it += 2) {
        int s0 = it * 8 + g, s1 = s0 + 8;
        int eA0 = cA[it * 8];
        int eA1 = cA[it * 8 + 8];
        int eB0 = cB[it * 8];
        int eB1 = cB[it * 8 + 8];
        eA0 = (s0 < degA) ? eA0 : NN;
        eA1 = (s1 < degA) ? eA1 : NN;
        eB0 = (s0 < degB) ? eB0 : NN;
        eB1 = (s1 < degB) ? eB1 : NN;
        uint4 u0 = *(const uint4*)(hp + (size_t)eA0 * 64);
        uint4 u1 = *(const uint4*)(hp + (size_t)eA1 * 64);
        uint4 u2 = *(const uint4*)(hp + (size_t)eB0 * 64);
        uint4 u3 = *(const uint4*)(hp + (size_t)eB1 * 64);
        aA[0] += bfu(u0.x & 0xffffu); aA[1] += bfu(u0.x >> 16);
        aA[2] += bfu(u0.y & 0xffffu); aA[3] += bfu(u0.y >> 16);
        aA[4] += bfu(u0.z & 0xffffu); aA[5] += bfu(u0.z >> 16);
        aA[6] += bfu(u0.w & 0xffffu); aA[7] += bfu(u0.w >> 16);
        aA[0] += bfu(u1.x & 0xffffu); aA[1] += bfu(u1.x >> 16);
        aA[2] += bfu(u1.y & 0xffffu); aA[3] += bfu(u1.y >> 16);
        aA[4] += bfu(u1.z & 0xffffu); aA[5] += bfu(u1.z >> 16);
        aA[6] += bfu(u1.w & 0xffffu); aA[7] += bfu(u1.w >> 16);
        aB[0] += bfu(u2.x & 0xffffu); aB[1] += bfu(u2.x >> 16);
        aB[2] += bfu(u2.y & 0xffffu); aB[3] += bfu(u2.y >> 16);
        aB[4] += bfu(u2.z & 0xffffu); aB[5] += bfu(u2.z >> 16);
        aB[6] += bfu(u2.w & 0xffffu); aB[7] += bfu(u2.w >> 16);
        aB[0] += bfu(u3.x & 0xffffu); aB[1] += bfu(u3.x >> 16);
        aB[2] += bfu(u3.y & 0xffffu); aB[3] += bfu(u3.y >> 16);
        aB[4] += bfu(u3.z & 0xffffu); aB[5] += bfu(u3.z >> 16);
        aB[6] += bfu(u3.w & 0xffffu); aB[7] += bfu(u3.w >> 16);
    }
#pragma unroll
    for (int m = 8; m <= 32; m <<= 1) {
#pragma unroll
        for (int k = 0; k < 8; ++k) {
            aA[k] += __shfl_xor(aA[k], m);
            aB[k] += __shfl_xor(aB[k], m);
        }
    }
    if (g < 2) {
        int nw = g ? n1 : n0;
        float o[8];
#pragma unroll
        for (int k = 0; k < 8; ++k) o[k] = g ? aB[k] : aA[k];
        float ri = r_in[nw];
        unsigned short ov[8];
        if (MODE == 0) {
            float ro = r_out[nw];
            float4 bA = *(const float4*)&bias[f8 * 8];
            float4 bB = *(const float4*)&bias[f8 * 8 + 4];
            float bb[8] = {bA.x, bA.y, bA.z, bA.w, bB.x, bB.y, bB.z, bB.w};
#pragma unroll
            for (int k = 0; k < 8; ++k)
                ov[k] = f2bf(fmaxf(fmaf(o[k], ri, bb[k]), 0.f) * ro);
        } else {
#pragma unroll
            for (int k = 0; k < 8; ++k) ov[k] = f2bf(o[k] * ri);
        }
        uint4 ow;
        ow.x = (unsigned)ov[0] | ((unsigned)ov[1] << 16);
        ow.y = (unsigned)ov[2] | ((unsigned)ov[3] << 16);
        ow.z = (unsigned)ov[4] | ((unsigned)ov[5] << 16);
        ow.w = (unsigned)ov[6] | ((unsigned)ov[7] << 16);
        *(uint4*)&o16[(size_t)nw * 64 + f8 * 8] = ow;
    }
}

// d=16 bf16 gather: 2 nodes/wave, 8 lanes/edge x uint (2 feats), same structure.
// out = agg*r_in + b2 (fp32 output)
__global__ __launch_bounds__(256) void k_gb16(const int* __restrict__ rowdesc,
                                              const int* __restrict__ csr,
                                              const unsigned short* __restrict__ C16,
                                              const float* __restrict__ r_in,
                                              const float* __restrict__ b2,
                                              float* __restrict__ out) {
    int tid = threadIdx.x;
    int wave = tid >> 6, lane = tid & 63;
    int n0 = (blockIdx.x * 4 + wave) * 2, n1 = n0 + 1;
    int rdA = rowdesc[n0], rdB = rowdesc[n1];
    int jbA = rdA >> 9, degA = rdA & 511;
    int jbB = rdB >> 9, degB = rdB & 511;
    int itn = max((degA + 7) >> 3, (degB + 7) >> 3);
    int g = lane >> 3, p = lane & 7;  // p: feature pair [0,8)
    const int* cA = csr + jbA + g;
    const int* cB = csr + jbB + g;
    const unsigned short* cp = C16 + p * 2;
    float a0A = 0.f, a1A = 0.f, a0B = 0.f, a1B = 0.f;
    for (int it = 0; it < itn; it += 2) {
        int s0 = it * 8 + g, s1 = s0 + 8;
        int eA0 = cA[it * 8];
        int eA1 = cA[it * 8 + 8];
        int eB0 = cB[it * 8];
        int eB1 = cB[it * 8 + 8];
        eA0 = (s0 < degA) ? eA0 : NN;
        eA1 = (s1 < degA) ? eA1 : NN;
        eB0 = (s0 < degB) ? eB0 : NN;
        eB1 = (s1 < degB) ? eB1 : NN;
        unsigned u0 = *(const unsigned*)(cp + (size_t)eA0 * 16);
        unsigned u1 = *(const unsigned*)(cp + (size_t)eA1 * 16);
        unsigned u2 = *(const unsigned*)(cp + (size_t)eB0 * 16);
        unsigned u3 = *(const unsigned*)(cp + (size_t)eB1 * 16);
        a0A += bfu(u0 & 0xffffu); a1A += bfu(u0 >> 16);
        a0A += bfu(u1 & 0xffffu); a1A += bfu(u1 >> 16);
        a0B += bfu(u2 & 0xffffu); a1B += bfu(u2 >> 16);
        a0B += bfu(u3 & 0xffffu); a1B += bfu(u3 >> 16);
    }
#pragma unroll
    for (int m = 8; m <= 32; m <<= 1) {
        a0A += __shfl_xor(a0A, m);
        a1A += __shfl_xor(a1A, m);
        a0B += __shfl_xor(a0B, m);
        a1B += __shfl_xor(a1B, m);
    }
    if (g < 2) {
        int nw = g ? n1 : n0;
        float x0 = g ? a0B : a0A;
        float x1 = g ? a1B : a1A;
        float ri = r_in[nw];
        float2 bb = *(const float2*)&b2[p * 2];
        float2 o;
        o.x = fmaf(x0, ri, bb.x);
        o.y = fmaf(x1, ri, bb.y);
        *(float2*)&out[(size_t)nw * 16 + p * 2] = o;
    }
}

extern "C" void kernel_launch(void* const* d_in, const int* in_sizes, int n_in,
                              void* d_out, int out_size, void* d_ws, size_t ws_size,
                              hipStream_t stream) {
    const float* feats = (const float*)d_in[0];
    const int* src = (const int*)d_in[1];
    const int* dst = (const int*)d_in[2];
    const float* W0 = (const float*)d_in[3];
    const float* b0 = (const float*)d_in[4];
    const float* W1 = (const float*)d_in[5];
    const float* b1 = (const float*)d_in[6];
    const float* W2 = (const float*)d_in[7];
    const float* b2 = (const float*)d_in[8];
    float* out = (float*)d_out;

    // ws (4B units):
    //   r_out[NN] | r_in[NN] | rowdesc[NN] | EB[NBUCK*BCAP + 64] (padded buckets;
    //   E2d then csr in-place) | E2s[NBUCK*BCAP bytes] | R1[32(NN+1)] (A then G) |
    //   R2[32(NN+1)] (B) | C16[8(NN+1)] | cur_d[NBUCK] cur_s[NBUCK]
    float* ws = (float*)d_ws;
    float* r_out = ws;
    float* r_in = ws + NN;
    int* rowdesc = (int*)(ws + 2 * NN);
    int* EB = (int*)(ws + 3 * NN);                       // NBUCK*BCAP + 64
    size_t ebw = (size_t)NBUCK * BCAP + 64;              // words
    unsigned char* E2s = (unsigned char*)(ws + 3 * NN + ebw);
    size_t e2sw = ((size_t)NBUCK * BCAP + 3) / 4;        // words
    float* R1 = ws + 3 * NN + ebw + e2sw;
    float* R2 = R1 + (size_t)32 * (NN + 1);
    float* Creg = R2 + (size_t)32 * (NN + 1);
    int* cur_d = (int*)(Creg + (size_t)8 * (NN + 1));
    int* cur_s = cur_d + NBUCK;

    unsigned short* A = (unsigned short*)R1;
    unsigned short* G = A;  // after k_gb64<0> consumes A, region reused for G
    unsigned short* B = (unsigned short*)R2;
    unsigned short* C16 = (unsigned short*)Creg;

    // build: padded buckets, cursors ARE the histogram (counts = cursor - base)
    k_init<<<1, 1024, 0, stream>>>(cur_d, cur_s, A, B, C16);
    k_pairs<<<2 * NPB, 512, 0, stream>>>(src, dst, cur_d, cur_s, EB, E2s);
    k_nodes<<<2 * NBUCK, 256, 0, stream>>>(EB, E2s, cur_d, cur_s, rowdesc, r_in, r_out);

    // layer 0
    k_gemm0<<<(NN + 63) / 64, 256, 0, stream>>>(feats, W0, r_out, A);
    k_gb64<0><<<NN / 8, 256, 0, stream>>>(rowdesc, EB, A, r_in, r_out, b0, B);

    // layer 1 (+ layer2 pre-GEMM)
    k_gb64<1><<<NN / 8, 256, 0, stream>>>(rowdesc, EB, B, r_in, r_out, b0, G);
    k_mlp<<<(NN + 63) / 64, 256, 0, stream>>>(G, W1, b1, W2, r_out, C16);

    // layer 2
    k_gb16<<<NN / 8, 256, 0, stream>>>(rowdesc, EB, C16, r_in, b2, out);
}